// Round 1
// baseline (1366.041 us; speedup 1.0000x reference)
//
#include <hip/hip_runtime.h>

typedef __bf16 bf16_t;
typedef __bf16 bf16x8 __attribute__((ext_vector_type(8)));
typedef __bf16 bf16x4 __attribute__((ext_vector_type(4)));
typedef float  f32x4  __attribute__((ext_vector_type(4)));

#define T_TOK 8192
#define DIM   1024
#define DFF   4096
#define NEXP  8

__device__ __forceinline__ void gll16(const void* g, void* l) {
    __builtin_amdgcn_global_load_lds(
        (const __attribute__((address_space(1))) char*)g,
        (__attribute__((address_space(3))) char*)l, 16, 0, 0);
}

// ---------------- x -> bf16 ----------------
__global__ void cvt_x_kernel(const float* __restrict__ x, bf16_t* __restrict__ xb, int n4) {
    int i = blockIdx.x * blockDim.x + threadIdx.x;
    int stride = gridDim.x * blockDim.x;
    for (; i < n4; i += stride) {
        float4 v = ((const float4*)x)[i];
        bf16x4 o;
        o[0] = (bf16_t)v.x; o[1] = (bf16_t)v.y; o[2] = (bf16_t)v.z; o[3] = (bf16_t)v.w;
        ((bf16x4*)xb)[i] = o;
    }
}

// ---------------- transpose + convert: src [R][C] f32 -> dst [C][R] bf16, per expert ----------------
__global__ void transpose_cvt_kernel(const float* __restrict__ src, bf16_t* __restrict__ dst,
                                     int R, int C) {
    __shared__ float t[32][33];
    int e = blockIdx.z;
    src += (size_t)e * R * C;
    dst += (size_t)e * R * C;
    int r0 = blockIdx.y * 32, c0 = blockIdx.x * 32;
    int tx = threadIdx.x & 31, ty = threadIdx.x >> 5;   // ty: 0..7
#pragma unroll
    for (int i = 0; i < 4; ++i) {
        int r = ty + i * 8;
        t[r][tx] = src[(size_t)(r0 + r) * C + c0 + tx];
    }
    __syncthreads();
#pragma unroll
    for (int i = 0; i < 4; ++i) {
        int cc = ty + i * 8;
        dst[(size_t)(c0 + cc) * R + r0 + tx] = (bf16_t)t[tx][cc];
    }
}

// ---------------- router: wave per token, f64 accumulation ----------------
__global__ __launch_bounds__(256) void router_kernel(
    const float* __restrict__ x, const float* __restrict__ noise,
    const float* __restrict__ w_route, const float* __restrict__ b_route,
    const float* __restrict__ w_noise, const float* __restrict__ b_noise,
    int* __restrict__ counts, int* __restrict__ lists, float* __restrict__ gate_tok)
{
    int wave = threadIdx.x >> 6;
    int lane = threadIdx.x & 63;
    int t = blockIdx.x * 4 + wave;
    if (t >= T_TOK) return;

    const float* xr = x + (size_t)t * DIM;
    double aR[NEXP], aN[NEXP];
#pragma unroll
    for (int e = 0; e < NEXP; ++e) { aR[e] = 0.0; aN[e] = 0.0; }

#pragma unroll 4
    for (int i = 0; i < 16; ++i) {
        int k = lane + i * 64;
        double xv = (double)xr[k];
        const float4* wr4 = (const float4*)(w_route + (size_t)k * 8);
        const float4* wn4 = (const float4*)(w_noise + (size_t)k * 8);
        float4 r0 = wr4[0], r1 = wr4[1];
        float4 n0 = wn4[0], n1 = wn4[1];
        aR[0] += xv * (double)r0.x; aR[1] += xv * (double)r0.y;
        aR[2] += xv * (double)r0.z; aR[3] += xv * (double)r0.w;
        aR[4] += xv * (double)r1.x; aR[5] += xv * (double)r1.y;
        aR[6] += xv * (double)r1.z; aR[7] += xv * (double)r1.w;
        aN[0] += xv * (double)n0.x; aN[1] += xv * (double)n0.y;
        aN[2] += xv * (double)n0.z; aN[3] += xv * (double)n0.w;
        aN[4] += xv * (double)n1.x; aN[5] += xv * (double)n1.y;
        aN[6] += xv * (double)n1.z; aN[7] += xv * (double)n1.w;
    }
#pragma unroll
    for (int e = 0; e < NEXP; ++e) {
        for (int s = 1; s < 64; s <<= 1) {
            aR[e] += __shfl_xor(aR[e], s);
            aN[e] += __shfl_xor(aN[e], s);
        }
    }
    if (lane == 0) {
        double nv[NEXP];
#pragma unroll
        for (int e = 0; e < NEXP; ++e) {
            double lg = aR[e] + (double)b_route[e];
            double nl = aN[e] + (double)b_noise[e];
            double sp = (nl > 30.0) ? nl : log1p(exp(nl));
            nv[e] = lg + (double)noise[(size_t)t * 8 + e] * sp;
        }
        int i1 = 0;
#pragma unroll
        for (int e = 1; e < NEXP; ++e) if (nv[e] > nv[i1]) i1 = e;
        int i2 = (i1 == 0) ? 1 : 0;
#pragma unroll
        for (int e = 0; e < NEXP; ++e) if (e != i1 && nv[e] > nv[i2]) i2 = e;
        double m = nv[i1];
        double e2 = exp(nv[i2] - m);
        double s = 1.0 + e2;
        gate_tok[2 * t + 0] = (float)(1.0 / s);
        gate_tok[2 * t + 1] = (float)(e2 / s);
        int p1 = atomicAdd(&counts[i1], 1);
        lists[i1 * T_TOK + p1] = 2 * t + 0;
        int p2 = atomicAdd(&counts[i2], 1);
        lists[i2 * T_TOK + p2] = 2 * t + 1;
    }
}

// ---------------- fused sparse GEMM: 128x128 tile, BK=64, 4 waves ----------------
// MODE 0: C = relu(gather(xb) @ w1t^T + b1) -> H rows (bf16), K=1024, N=4096
// MODE 1: out[token] += gate * (gather(H) @ w2t^T + b2),   K=4096, N=1024
template<int K, int MODE>
__global__ __launch_bounds__(256) void moe_gemm_kernel(
    const bf16_t* __restrict__ Asrc, const bf16_t* __restrict__ Wt,
    const float* __restrict__ bias,
    const int* __restrict__ counts, const int* __restrict__ lists,
    const float* __restrict__ gate_tok,
    bf16_t* __restrict__ Hout, float* __restrict__ out)
{
    constexpr int N = (MODE == 0) ? DFF : DIM;
    int e = blockIdx.z;
    int cnt = counts[e];
    int m0 = blockIdx.x * 128;
    if (m0 >= cnt) return;
    int n0 = blockIdx.y * 128;
    const int* list = lists + e * T_TOK;
    const bf16_t* W = Wt + (size_t)e * N * K;

    __shared__ __attribute__((aligned(16))) bf16_t Ah[128 * 64];
    __shared__ __attribute__((aligned(16))) bf16_t Bh[128 * 64];

    int tid = threadIdx.x;
    int lane = tid & 63;
    int wave = tid >> 6;
    int wr = wave >> 1, wc = wave & 1;

    // staging source pointers (row part), per chunk handled by this lane
    const bf16_t* pA[4];
    const bf16_t* pB[4];
#pragma unroll
    for (int i = 0; i < 4; ++i) {
        int c = wave * 4 + i;            // chunk 0..15 (1KB each)
        int elem = c * 512 + lane * 8;   // bf16 element index in 128x64 tile
        int r = elem >> 6;
        int kc = elem & 63;
        int idx = m0 + r;
        if (idx >= cnt) idx = cnt - 1;
        int entry = list[idx];
        size_t arow = (MODE == 0) ? (size_t)(entry >> 1) : (size_t)entry;
        pA[i] = Asrc + arow * (size_t)K + kc;
        pB[i] = W + (size_t)(n0 + r) * K + kc;
    }

    f32x4 acc[4][4];
#pragma unroll
    for (int m = 0; m < 4; ++m)
#pragma unroll
        for (int n = 0; n < 4; ++n)
            acc[m][n] = (f32x4){0.f, 0.f, 0.f, 0.f};

    for (int kt = 0; kt < K / 64; ++kt) {
        int k0 = kt * 64;
#pragma unroll
        for (int i = 0; i < 4; ++i) {
            int c = wave * 4 + i;
            gll16(pA[i] + k0, Ah + c * 512);
            gll16(pB[i] + k0, Bh + c * 512);
        }
        __syncthreads();
#pragma unroll
        for (int kk = 0; kk < 2; ++kk) {
            bf16x8 a[4], b[4];
            int kb = kk * 32 + (lane >> 4) * 8;
#pragma unroll
            for (int m = 0; m < 4; ++m)
                a[m] = *(const bf16x8*)(Ah + (wr * 64 + m * 16 + (lane & 15)) * 64 + kb);
#pragma unroll
            for (int n = 0; n < 4; ++n)
                b[n] = *(const bf16x8*)(Bh + (wc * 64 + n * 16 + (lane & 15)) * 64 + kb);
#pragma unroll
            for (int m = 0; m < 4; ++m)
#pragma unroll
                for (int n = 0; n < 4; ++n)
                    acc[m][n] = __builtin_amdgcn_mfma_f32_16x16x32_bf16(a[m], b[n], acc[m][n], 0, 0, 0);
        }
        __syncthreads();
    }

    // epilogue
    int ln15 = lane & 15, l4 = lane >> 4;
#pragma unroll
    for (int m = 0; m < 4; ++m) {
#pragma unroll
        for (int j = 0; j < 4; ++j) {
            int grow = m0 + wr * 64 + m * 16 + l4 * 4 + j;
            if (grow >= cnt) continue;
            int entry = list[grow];
#pragma unroll
            for (int n = 0; n < 4; ++n) {
                int gcol = n0 + wc * 64 + n * 16 + ln15;
                float v = acc[m][n][j];
                if constexpr (MODE == 0) {
                    v += bias[e * N + gcol];
                    v = fmaxf(v, 0.f);
                    Hout[(size_t)entry * DFF + gcol] = (bf16_t)v;
                } else {
                    v += bias[e * N + gcol];
                    float g = gate_tok[entry];
                    atomicAdd(&out[(size_t)(entry >> 1) * DIM + gcol], g * v);
                }
            }
        }
    }
}

extern "C" void kernel_launch(void* const* d_in, const int* in_sizes, int n_in,
                              void* d_out, int out_size, void* d_ws, size_t ws_size,
                              hipStream_t stream) {
    const float* x       = (const float*)d_in[0];
    const float* noise   = (const float*)d_in[1];
    const float* w_route = (const float*)d_in[2];
    const float* b_route = (const float*)d_in[3];
    const float* w_noise = (const float*)d_in[4];
    const float* b_noise = (const float*)d_in[5];
    const float* w1      = (const float*)d_in[6];
    const float* b1      = (const float*)d_in[7];
    const float* w2      = (const float*)d_in[8];
    const float* b2      = (const float*)d_in[9];
    float* out = (float*)d_out;

    char* ws = (char*)d_ws;
    size_t off = 0;
    auto alloc = [&](size_t bytes) {
        off = (off + 255) & ~(size_t)255;
        size_t r = off; off += bytes; return r;
    };
    int*    counts   = (int*)   (ws + alloc(32));
    int*    lists    = (int*)   (ws + alloc((size_t)NEXP * T_TOK * 4));
    float*  gate_tok = (float*) (ws + alloc((size_t)T_TOK * 2 * 4));
    bf16_t* xb       = (bf16_t*)(ws + alloc((size_t)T_TOK * DIM * 2));
    bf16_t* w1t      = (bf16_t*)(ws + alloc((size_t)NEXP * DFF * DIM * 2));
    bf16_t* w2t      = (bf16_t*)(ws + alloc((size_t)NEXP * DIM * DFF * 2));
    bf16_t* H        = (bf16_t*)(ws + alloc((size_t)T_TOK * 2 * DFF * 2));
    (void)ws_size; (void)in_sizes; (void)n_in; (void)out_size;

    hipMemsetAsync(counts, 0, 32, stream);
    hipMemsetAsync(out, 0, (size_t)T_TOK * DIM * 4, stream);

    cvt_x_kernel<<<2048, 256, 0, stream>>>(x, xb, T_TOK * DIM / 4);

    transpose_cvt_kernel<<<dim3(DFF / 32, DIM / 32, NEXP), 256, 0, stream>>>(w1, w1t, DIM, DFF);
    transpose_cvt_kernel<<<dim3(DIM / 32, DFF / 32, NEXP), 256, 0, stream>>>(w2, w2t, DFF, DIM);

    router_kernel<<<T_TOK / 4, 256, 0, stream>>>(x, noise, w_route, b_route, w_noise, b_noise,
                                                 counts, lists, gate_tok);

    moe_gemm_kernel<DIM, 0><<<dim3(64, DFF / 128, NEXP), 256, 0, stream>>>(
        xb, w1t, b1, counts, lists, gate_tok, H, nullptr);
    moe_gemm_kernel<DFF, 1><<<dim3(64, DIM / 128, NEXP), 256, 0, stream>>>(
        H, w2t, b2, counts, lists, gate_tok, nullptr, out);
}

// Round 2
// 1276.526 us; speedup vs baseline: 1.0701x; 1.0701x over previous
//
#include <hip/hip_runtime.h>

typedef __bf16 bf16_t;
typedef __bf16 bf16x8 __attribute__((ext_vector_type(8)));
typedef __bf16 bf16x4 __attribute__((ext_vector_type(4)));
typedef float  f32x4  __attribute__((ext_vector_type(4)));

#define T_TOK 8192
#define DIM   1024
#define DFF   4096
#define NEXP  8

__device__ __forceinline__ void gll16(const void* g, void* l) {
    __builtin_amdgcn_global_load_lds(
        (const __attribute__((address_space(1))) char*)g,
        (__attribute__((address_space(3))) char*)l, 16, 0, 0);
}

// ---------------- x -> bf16 ----------------
__global__ void cvt_x_kernel(const float* __restrict__ x, bf16_t* __restrict__ xb, int n4) {
    int i = blockIdx.x * blockDim.x + threadIdx.x;
    int stride = gridDim.x * blockDim.x;
    for (; i < n4; i += stride) {
        float4 v = ((const float4*)x)[i];
        bf16x4 o;
        o[0] = (bf16_t)v.x; o[1] = (bf16_t)v.y; o[2] = (bf16_t)v.z; o[3] = (bf16_t)v.w;
        ((bf16x4*)xb)[i] = o;
    }
}

// ---------------- transpose + convert: src [R][C] f32 -> dst [C][R] bf16, per expert ----------------
__global__ void transpose_cvt_kernel(const float* __restrict__ src, bf16_t* __restrict__ dst,
                                     int R, int C) {
    __shared__ float t[32][33];
    int e = blockIdx.z;
    src += (size_t)e * R * C;
    dst += (size_t)e * R * C;
    int r0 = blockIdx.y * 32, c0 = blockIdx.x * 32;
    int tx = threadIdx.x & 31, ty = threadIdx.x >> 5;   // ty: 0..7
#pragma unroll
    for (int i = 0; i < 4; ++i) {
        int r = ty + i * 8;
        t[r][tx] = src[(size_t)(r0 + r) * C + c0 + tx];
    }
    __syncthreads();
#pragma unroll
    for (int i = 0; i < 4; ++i) {
        int cc = ty + i * 8;
        dst[(size_t)(c0 + cc) * R + r0 + tx] = (bf16_t)t[tx][cc];
    }
}

// ---------------- router: wave per token, f64 accumulation ----------------
__global__ __launch_bounds__(256) void router_kernel(
    const float* __restrict__ x, const float* __restrict__ noise,
    const float* __restrict__ w_route, const float* __restrict__ b_route,
    const float* __restrict__ w_noise, const float* __restrict__ b_noise,
    int* __restrict__ counts, int* __restrict__ lists, float* __restrict__ gate_tok)
{
    int wave = threadIdx.x >> 6;
    int lane = threadIdx.x & 63;
    int t = blockIdx.x * 4 + wave;
    if (t >= T_TOK) return;

    const float* xr = x + (size_t)t * DIM;
    double aR[NEXP], aN[NEXP];
#pragma unroll
    for (int e = 0; e < NEXP; ++e) { aR[e] = 0.0; aN[e] = 0.0; }

#pragma unroll 4
    for (int i = 0; i < 16; ++i) {
        int k = lane + i * 64;
        double xv = (double)xr[k];
        const float4* wr4 = (const float4*)(w_route + (size_t)k * 8);
        const float4* wn4 = (const float4*)(w_noise + (size_t)k * 8);
        float4 r0 = wr4[0], r1 = wr4[1];
        float4 n0 = wn4[0], n1 = wn4[1];
        aR[0] += xv * (double)r0.x; aR[1] += xv * (double)r0.y;
        aR[2] += xv * (double)r0.z; aR[3] += xv * (double)r0.w;
        aR[4] += xv * (double)r1.x; aR[5] += xv * (double)r1.y;
        aR[6] += xv * (double)r1.z; aR[7] += xv * (double)r1.w;
        aN[0] += xv * (double)n0.x; aN[1] += xv * (double)n0.y;
        aN[2] += xv * (double)n0.z; aN[3] += xv * (double)n0.w;
        aN[4] += xv * (double)n1.x; aN[5] += xv * (double)n1.y;
        aN[6] += xv * (double)n1.z; aN[7] += xv * (double)n1.w;
    }
#pragma unroll
    for (int e = 0; e < NEXP; ++e) {
        for (int s = 1; s < 64; s <<= 1) {
            aR[e] += __shfl_xor(aR[e], s);
            aN[e] += __shfl_xor(aN[e], s);
        }
    }
    if (lane == 0) {
        double nv[NEXP];
#pragma unroll
        for (int e = 0; e < NEXP; ++e) {
            double lg = aR[e] + (double)b_route[e];
            double nl = aN[e] + (double)b_noise[e];
            double sp = (nl > 30.0) ? nl : log1p(exp(nl));
            nv[e] = lg + (double)noise[(size_t)t * 8 + e] * sp;
        }
        int i1 = 0;
#pragma unroll
        for (int e = 1; e < NEXP; ++e) if (nv[e] > nv[i1]) i1 = e;
        int i2 = (i1 == 0) ? 1 : 0;
#pragma unroll
        for (int e = 0; e < NEXP; ++e) if (e != i1 && nv[e] > nv[i2]) i2 = e;
        double m = nv[i1];
        double e2 = exp(nv[i2] - m);
        double s = 1.0 + e2;
        gate_tok[2 * t + 0] = (float)(1.0 / s);
        gate_tok[2 * t + 1] = (float)(e2 / s);
        int p1 = atomicAdd(&counts[i1], 1);
        lists[i1 * T_TOK + p1] = 2 * t + 0;
        int p2 = atomicAdd(&counts[i2], 1);
        lists[i2 * T_TOK + p2] = 2 * t + 1;
    }
}

// ---------------- fused sparse GEMM: 128x128 tile, BK=64, 4 waves ----------------
// LDS tiles are XOR-swizzled (T2): 16B slot s at row r holds global slot s^(r&7).
// Write side: global_load_lds dest stays LINEAR; the per-lane GLOBAL source
// column is pre-swizzled (row&7 == lane>>3 within each 1KB chunk).
// Read side: ds_read_b128 at slot (chunk ^ (row&7)); row&7 == lane&7 here.
// MODE 0: C = relu(gather(xb) @ w1t^T + b1) -> H rows (bf16), K=1024, N=4096
// MODE 1: out[token] += gate * (gather(H) @ w2t^T + b2),   K=4096, N=1024
template<int K, int MODE>
__global__ __launch_bounds__(256) void moe_gemm_kernel(
    const bf16_t* __restrict__ Asrc, const bf16_t* __restrict__ Wt,
    const float* __restrict__ bias,
    const int* __restrict__ counts, const int* __restrict__ lists,
    const float* __restrict__ gate_tok,
    bf16_t* __restrict__ Hout, float* __restrict__ out)
{
    constexpr int N = (MODE == 0) ? DFF : DIM;
    int e = blockIdx.z;
    int cnt = counts[e];
    int m0 = blockIdx.x * 128;
    if (m0 >= cnt) return;
    int n0 = blockIdx.y * 128;
    const int* list = lists + e * T_TOK;
    const bf16_t* W = Wt + (size_t)e * N * K;

    __shared__ __attribute__((aligned(16))) bf16_t Ah[128 * 64];
    __shared__ __attribute__((aligned(16))) bf16_t Bh[128 * 64];

    int tid = threadIdx.x;
    int lane = tid & 63;
    int wave = tid >> 6;
    int wr = wave >> 1, wc = wave & 1;

    // staging source pointers; column pre-swizzled so linear LDS ends up
    // holding slot s^(row&7) at (row, s).
    int kcs = (((lane & 7) ^ (lane >> 3)) << 3);   // swizzled bf16 col offset
    const bf16_t* pA[4];
    const bf16_t* pB[4];
#pragma unroll
    for (int i = 0; i < 4; ++i) {
        int c = wave * 4 + i;            // chunk 0..15 (1KB each, 8 rows)
        int r = c * 8 + (lane >> 3);     // row within 128-row tile
        int idx = m0 + r;
        if (idx >= cnt) idx = cnt - 1;
        int entry = list[idx];
        size_t arow = (MODE == 0) ? (size_t)(entry >> 1) : (size_t)entry;
        pA[i] = Asrc + arow * (size_t)K + kcs;
        pB[i] = W + (size_t)(n0 + r) * K + kcs;
    }

    f32x4 acc[4][4];
#pragma unroll
    for (int m = 0; m < 4; ++m)
#pragma unroll
        for (int n = 0; n < 4; ++n)
            acc[m][n] = (f32x4){0.f, 0.f, 0.f, 0.f};

    int g = lane >> 4;
    int ln15 = lane & 15;

    for (int kt = 0; kt < K / 64; ++kt) {
        int k0 = kt * 64;
#pragma unroll
        for (int i = 0; i < 4; ++i) {
            int c = wave * 4 + i;
            gll16(pA[i] + k0, Ah + c * 512);
            gll16(pB[i] + k0, Bh + c * 512);
        }
        __syncthreads();
#pragma unroll
        for (int kk = 0; kk < 2; ++kk) {
            bf16x8 a[4], b[4];
            int sw = (((kk * 4 + g) ^ (lane & 7)) << 3);  // swizzled 16B slot
#pragma unroll
            for (int m = 0; m < 4; ++m)
                a[m] = *(const bf16x8*)(Ah + (wr * 64 + m * 16 + ln15) * 64 + sw);
#pragma unroll
            for (int n = 0; n < 4; ++n)
                b[n] = *(const bf16x8*)(Bh + (wc * 64 + n * 16 + ln15) * 64 + sw);
#pragma unroll
            for (int m = 0; m < 4; ++m)
#pragma unroll
                for (int n = 0; n < 4; ++n)
                    acc[m][n] = __builtin_amdgcn_mfma_f32_16x16x32_bf16(a[m], b[n], acc[m][n], 0, 0, 0);
        }
        __syncthreads();
    }

    // epilogue
    int l4 = lane >> 4;
#pragma unroll
    for (int m = 0; m < 4; ++m) {
#pragma unroll
        for (int j = 0; j < 4; ++j) {
            int grow = m0 + wr * 64 + m * 16 + l4 * 4 + j;
            if (grow >= cnt) continue;
            int entry = list[grow];
#pragma unroll
            for (int n = 0; n < 4; ++n) {
                int gcol = n0 + wc * 64 + n * 16 + ln15;
                float v = acc[m][n][j];
                if constexpr (MODE == 0) {
                    v += bias[e * N + gcol];
                    v = fmaxf(v, 0.f);
                    Hout[(size_t)entry * DFF + gcol] = (bf16_t)v;
                } else {
                    v += bias[e * N + gcol];
                    float gt = gate_tok[entry];
                    atomicAdd(&out[(size_t)(entry >> 1) * DIM + gcol], gt * v);
                }
            }
        }
    }
}

extern "C" void kernel_launch(void* const* d_in, const int* in_sizes, int n_in,
                              void* d_out, int out_size, void* d_ws, size_t ws_size,
                              hipStream_t stream) {
    const float* x       = (const float*)d_in[0];
    const float* noise   = (const float*)d_in[1];
    const float* w_route = (const float*)d_in[2];
    const float* b_route = (const float*)d_in[3];
    const float* w_noise = (const float*)d_in[4];
    const float* b_noise = (const float*)d_in[5];
    const float* w1      = (const float*)d_in[6];
    const float* b1      = (const float*)d_in[7];
    const float* w2      = (const float*)d_in[8];
    const float* b2      = (const float*)d_in[9];
    float* out = (float*)d_out;

    char* ws = (char*)d_ws;
    size_t off = 0;
    auto alloc = [&](size_t bytes) {
        off = (off + 255) & ~(size_t)255;
        size_t r = off; off += bytes; return r;
    };
    int*    counts   = (int*)   (ws + alloc(32));
    int*    lists    = (int*)   (ws + alloc((size_t)NEXP * T_TOK * 4));
    float*  gate_tok = (float*) (ws + alloc((size_t)T_TOK * 2 * 4));
    bf16_t* xb       = (bf16_t*)(ws + alloc((size_t)T_TOK * DIM * 2));
    bf16_t* w1t      = (bf16_t*)(ws + alloc((size_t)NEXP * DFF * DIM * 2));
    bf16_t* w2t      = (bf16_t*)(ws + alloc((size_t)NEXP * DIM * DFF * 2));
    bf16_t* H        = (bf16_t*)(ws + alloc((size_t)T_TOK * 2 * DFF * 2));
    (void)ws_size; (void)in_sizes; (void)n_in; (void)out_size;

    hipMemsetAsync(counts, 0, 32, stream);
    hipMemsetAsync(out, 0, (size_t)T_TOK * DIM * 4, stream);

    cvt_x_kernel<<<2048, 256, 0, stream>>>(x, xb, T_TOK * DIM / 4);

    transpose_cvt_kernel<<<dim3(DFF / 32, DIM / 32, NEXP), 256, 0, stream>>>(w1, w1t, DIM, DFF);
    transpose_cvt_kernel<<<dim3(DIM / 32, DFF / 32, NEXP), 256, 0, stream>>>(w2, w2t, DFF, DIM);

    router_kernel<<<T_TOK / 4, 256, 0, stream>>>(x, noise, w_route, b_route, w_noise, b_noise,
                                                 counts, lists, gate_tok);

    moe_gemm_kernel<DIM, 0><<<dim3(64, DFF / 128, NEXP), 256, 0, stream>>>(
        xb, w1t, b1, counts, lists, gate_tok, H, nullptr);
    moe_gemm_kernel<DFF, 1><<<dim3(64, DIM / 128, NEXP), 256, 0, stream>>>(
        H, w2t, b2, counts, lists, gate_tok, nullptr, out);
}